// Round 18
// baseline (149.951 us; speedup 1.0000x reference)
//
#include <hip/hip_runtime.h>
#include <hip/hip_bf16.h>
#include <math.h>

#define NW 2   // samples per 128-thread block (1 per wave)

typedef __attribute__((ext_vector_type(8)))  short bf16x8;
typedef __attribute__((ext_vector_type(16))) float f32x16;

__device__ __forceinline__ float bperm(int srcidx, float x) {
    return __int_as_float(__builtin_amdgcn_ds_bpermute(srcidx, __float_as_int(x)));
}
__device__ __forceinline__ unsigned bpermu(int srcidx, unsigned x) {
    return (unsigned)__builtin_amdgcn_ds_bpermute(srcidx, (int)x);
}
// f32 -> bf16 bits, RNE (manual, bit-deterministic: probes)
__device__ __forceinline__ unsigned f2bfu(float x) {
    unsigned u = __float_as_uint(x);
    return (u + 0x7fffu + ((u >> 16) & 1u)) >> 16;
}
__device__ __forceinline__ float bf2f(unsigned hb) { return __uint_as_float(hb << 16); }
__device__ __forceinline__ unsigned short bfb(float x) {
    __hip_bfloat16 b = __float2bfloat16(x);
    unsigned short u;
    __builtin_memcpy(&u, &b, sizeof(u));
    return u;
}
__device__ __forceinline__ void split(float x, unsigned short& hb, unsigned short& lb) {
    hb = bfb(x);
    float lo = x - bf2f(hb);
    lb = bfb(lo);
}
template <int JM>
__device__ __forceinline__ bf16x8 pick(const unsigned short (&s)[8]) {
    bf16x8 r;
    #pragma unroll
    for (int j = 0; j < 8; ++j) {
        int idx = (JM == 0) ? j : (JM == 1 ? (j ^ 4) : (7 - j));
        r[j] = (short)s[idx];
    }
    return r;
}
// two ds_read_b64 -> one bf16x8 (stride-36 planes: 2-way conflicts = free)
__device__ __forceinline__ bf16x8 rd8(const unsigned short* p) {
    uint2 a = *reinterpret_cast<const uint2*>(p);
    uint2 b = *reinterpret_cast<const uint2*>(p + 4);
    union { unsigned u[4]; bf16x8 v; } r;
    r.u[0] = a.x; r.u[1] = a.y; r.u[2] = b.x; r.u[3] = b.y;
    return r.v;
}
union U4V8 { unsigned u[4]; bf16x8 v; };

// logm via Chebyshev deg-10 of log on [1,8]: S=(M-4.5I)/3.5, T_{k+1}=2*S*T_k-T_{k-1}.
// A-operand S: hi/lo bf16 split in registers. B-operand T_k: bf16, REBUILT IN
// REGISTERS each step (R16 was serial-latency-bound on the LDS store->RAW->read
// chain, ~2800 cyc/step). C-layout lane c holds column c = next B column c; the
// missing row-quads live in lane^32 -> 4 ds_bpermute + cndmask assembly (~100 cyc).
// Gated on rws[] == standard map; else proven R16 LDS path. Layout discovered by
// 3 one-MFMA probes (proven R10+, absmax 0.0).
__global__ __launch_bounds__(128, 1)
void geo_loss_mfma(const float* __restrict__ yhat, const float* __restrict__ y,
                   float* __restrict__ out, int B)
{
    __shared__ unsigned short TA[NW][32][36];   // chain-1 (yhat) plane (init + fallback)
    __shared__ unsigned short TB[NW][32][36];   // chain-2 (y)    plane
    __shared__ float bl[NW];

    const int t    = threadIdx.x;
    const int w    = t >> 6;
    const int lane = t & 63;
    const int c    = lane & 31;
    const int h    = lane >> 5;
    const bool hi  = (h != 0);
    const int xidx = (lane ^ 32) << 2;   // partner half-lane for bpermute

    int b = blockIdx.x * NW + w;
    const float valid = (b < B) ? 1.f : 0.f;
    if (b >= B) b = B - 1;

    const f32x16 zz = {0.f,0.f,0.f,0.f,0.f,0.f,0.f,0.f,0.f,0.f,0.f,0.f,0.f,0.f,0.f,0.f};
    float sent = 0.f;

    // ---- probe 1: relative A/B slot-labeling delta (6 hypotheses) ----
    bf16x8 pa;
    #pragma unroll
    for (int j = 0; j < 8; ++j) pa[j] = (short)f2bfu((float)(8*h + j + 1));
    int sel = -1;
    #pragma unroll
    for (int cand = 0; cand < 6; ++cand) {
        const int hfc = cand & 1, jmc = cand >> 1;
        bf16x8 pb;
        #pragma unroll
        for (int j = 0; j < 8; ++j) {
            int hh = hfc ? (1 - h) : h;
            int jj = (jmc == 0) ? j : (jmc == 1 ? (j ^ 4) : (7 - j));
            float lab = (float)(8*hh + jj + 1);
            pb[j] = (short)f2bfu(lab * lab);
        }
        f32x16 pr = __builtin_amdgcn_mfma_f32_32x32x16_bf16(pa, pb, zz, 0, 0, 0);
        if (sel < 0 && __ballot(pr[0] != 18496.f) == 0ull) sel = cand;
    }
    if (sel < 0) { sent += 1.0e10f; sel = 0; }
    const int hf = sel & 1, jm = sel >> 1;

    // ---- probe 2: C (lane,reg) -> row map ----
    bf16x8 pa2, pb1;
    #pragma unroll
    for (int j = 0; j < 8; ++j) {
        pa2[j] = (short)f2bfu((float)(c + 1));
        pb1[j] = (short)f2bfu(1.f);
    }
    f32x16 r2 = __builtin_amdgcn_mfma_f32_32x32x16_bf16(pa2, pb1, zz, 0, 0, 0);
    int rws[16]; bool ok2 = true;
    #pragma unroll
    for (int i = 0; i < 16; ++i) {
        float q = r2[i] * 0.0625f;
        int ri = (int)(q + 0.5f);
        ok2 = ok2 && (fabsf(q - (float)ri) < 1e-3f) && ri >= 1 && ri <= 32;
        rws[i] = ri - 1;
    }
    if (__ballot(!ok2) != 0ull) {
        sent += 2.0e10f;
        #pragma unroll
        for (int i = 0; i < 16; ++i) rws[i] = (i & 3) + 8*(i >> 2) + 4*h;
    }

    // ---- probe 3: C lane -> col map ----
    f32x16 r3 = __builtin_amdgcn_mfma_f32_32x32x16_bf16(pb1, pa2, zz, 0, 0, 0);
    int colstar;
    {
        float q = r3[0] * 0.0625f;
        int ci = (int)(q + 0.5f);
        bool ok3 = (fabsf(q - (float)ci) < 1e-3f) && ci >= 1 && ci <= 32;
        colstar = ci - 1;
        if (__ballot(!ok3) != 0ull) { sent += 4.0e10f; colstar = c; }
    }

    // standard-map check (enables in-register B rebuild) + quad bases for fallback
    bool stdl = true;
    int rq[4];
    #pragma unroll
    for (int i = 0; i < 16; ++i)
        stdl = stdl && (rws[i] == ((i & 3) + 8*(i >> 2) + 4*h));
    #pragma unroll
    for (int q = 0; q < 4; ++q) rq[q] = rws[4*q];
    const bool stdok = (__ballot(!stdl) == 0ull);
    if (!stdok) sent += 8.0e10f;   // diagnosable: slow-but-correct path engaged
    if (lane == 0 && sent > 0.f) atomicAdd(out, sent);

    const float INV = 0.2857142857142857f;   // 1/3.5
    const int abase = 8 * (h ^ hf);

    // ---- load S rows; A-frags hi/lo in regs; stage bf16 S (=T1) to planes ----
    bf16x8 A1h0, A1l0, A1h1, A1l1, A2h0, A2l0, A2h1, A2l1;
    #pragma unroll
    for (int m = 0; m < 2; ++m) {
        const float* Mp = (m == 0 ? yhat : y) + ((size_t)b << 10);
        unsigned short H0[8], L0[8], H1[8], L1[8];
        const float4* p0 = reinterpret_cast<const float4*>(Mp + c*32 + abase);
        float4 q0 = p0[0], q1 = p0[1];
        float f0[8] = {q0.x,q0.y,q0.z,q0.w, q1.x,q1.y,q1.z,q1.w};
        const float4* p1 = reinterpret_cast<const float4*>(Mp + c*32 + 16 + abase);
        float4 q2 = p1[0], q3 = p1[1];
        float f1[8] = {q2.x,q2.y,q2.z,q2.w, q3.x,q3.y,q3.z,q3.w};
        #pragma unroll
        for (int e = 0; e < 8; ++e) {
            int k0 = abase + e, k1 = 16 + abase + e;
            float x0 = (f0[e] - ((k0 == c) ? 4.5f : 0.f)) * INV;
            float x1 = (f1[e] - ((k1 == c) ? 4.5f : 0.f)) * INV;
            split(x0, H0[e], L0[e]);
            split(x1, H1[e], L1[e]);
        }
        unsigned short (*pl)[36] = (m == 0) ? TA[w] : TB[w];
        *reinterpret_cast<uint2*>(&pl[c][abase]) =
            make_uint2((unsigned)H0[0] | ((unsigned)H0[1] << 16),
                       (unsigned)H0[2] | ((unsigned)H0[3] << 16));
        *reinterpret_cast<uint2*>(&pl[c][abase + 4]) =
            make_uint2((unsigned)H0[4] | ((unsigned)H0[5] << 16),
                       (unsigned)H0[6] | ((unsigned)H0[7] << 16));
        *reinterpret_cast<uint2*>(&pl[c][16 + abase]) =
            make_uint2((unsigned)H1[0] | ((unsigned)H1[1] << 16),
                       (unsigned)H1[2] | ((unsigned)H1[3] << 16));
        *reinterpret_cast<uint2*>(&pl[c][16 + abase + 4]) =
            make_uint2((unsigned)H1[4] | ((unsigned)H1[5] << 16),
                       (unsigned)H1[6] | ((unsigned)H1[7] << 16));
        bf16x8 ah0, al0, ah1, al1;
        if (jm == 0)      { ah0=pick<0>(H0); al0=pick<0>(L0); ah1=pick<0>(H1); al1=pick<0>(L1); }
        else if (jm == 1) { ah0=pick<1>(H0); al0=pick<1>(L0); ah1=pick<1>(H1); al1=pick<1>(L1); }
        else              { ah0=pick<2>(H0); al0=pick<2>(L0); ah1=pick<2>(H1); al1=pick<2>(L1); }
        if (m == 0) { A1h0=ah0; A1l0=al0; A1h1=ah1; A1l1=al1; }
        else        { A2h0=ah0; A2l0=al0; A2h1=ah1; A2l1=al1; }
    }

    // ---- init recurrence state (T1 = S from plane, bf16 precision) ----
    float U1[16], V1[16], P1[16], U2[16], V2[16], P2[16];
    #pragma unroll
    for (int i = 0; i < 16; ++i) {
        float dg = (rws[i] == colstar) ? 1.f : 0.f;
        float tv1 = bf2f(TA[w][colstar][rws[i]]);
        float tv2 = bf2f(TB[w][colstar][rws[i]]);
        V1[i] = tv1; V2[i] = tv2; U1[i] = dg; U2[i] = dg;
        P1[i] = fmaf(0.95518452f, tv1, 1.2986135f * dg);
        P2[i] = fmaf(0.95518452f, tv2, 1.2986135f * dg);
    }

    // ---- initial B-frags (T1 = S) from planes, natural row order ----
    bf16x8 B10 = rd8(&TA[w][c][8*h]);
    bf16x8 B11 = rd8(&TA[w][c][16 + 8*h]);
    bf16x8 B20 = rd8(&TB[w][c][8*h]);
    bf16x8 B21 = rd8(&TB[w][c][16 + 8*h]);

    // in-register B rebuild from C-space W (standard map):
    // W[i] holds row (i&3)+8*(i>>2)+4h of column c. pk[p]=(W[2p],W[2p+1]) packs rows:
    // h=0: pk0..7 = (0,1)(2,3)(8,9)(10,11)(16,17)(18,19)(24,25)(26,27)
    // h=1: same +4. B half0 needs rows 8h+0..7; half1 rows 16+8h+0..7.
    // Missing quads live in lane^32: h0 sends pk2,pk3,pk6,pk7; h1 sends pk0,pk1,pk4,pk5.
    auto BUILD = [&](const float (&W)[16], bf16x8& B0, bf16x8& B1) {
        unsigned pk[8];
        #pragma unroll
        for (int p = 0; p < 8; ++p)
            pk[p] = (unsigned)bfb(W[2*p]) | ((unsigned)bfb(W[2*p+1]) << 16);
        unsigned o0 = hi ? pk[0] : pk[2];
        unsigned o1 = hi ? pk[1] : pk[3];
        unsigned o2 = hi ? pk[4] : pk[6];
        unsigned o3 = hi ? pk[5] : pk[7];
        unsigned r0 = bpermu(xidx, o0);
        unsigned r1 = bpermu(xidx, o1);
        unsigned r2b = bpermu(xidx, o2);
        unsigned r3b = bpermu(xidx, o3);
        U4V8 b0, b1;
        b0.u[0] = hi ? r0   : pk[0];
        b0.u[1] = hi ? r1   : pk[1];
        b0.u[2] = hi ? pk[2] : r0;
        b0.u[3] = hi ? pk[3] : r1;
        b1.u[0] = hi ? r2b  : pk[4];
        b1.u[1] = hi ? r3b  : pk[5];
        b1.u[2] = hi ? pk[6] : r2b;
        b1.u[3] = hi ? pk[7] : r3b;
        B0 = b0.v; B1 = b1.v;
    };
    // fallback (non-standard map): proven R16 LDS store+read
    auto BUILD_LDS = [&](const float (&W1)[16], const float (&W2)[16]) {
        #pragma unroll
        for (int q = 0; q < 4; ++q) {
            int r0 = rq[q];
            unsigned short b1v[4], b2v[4];
            #pragma unroll
            for (int e = 0; e < 4; ++e) {
                b1v[e] = bfb(W1[4*q+e]);
                b2v[e] = bfb(W2[4*q+e]);
            }
            *reinterpret_cast<uint2*>(&TA[w][colstar][r0]) =
                make_uint2((unsigned)b1v[0] | ((unsigned)b1v[1] << 16),
                           (unsigned)b1v[2] | ((unsigned)b1v[3] << 16));
            *reinterpret_cast<uint2*>(&TB[w][colstar][r0]) =
                make_uint2((unsigned)b2v[0] | ((unsigned)b2v[1] << 16),
                           (unsigned)b2v[2] | ((unsigned)b2v[3] << 16));
        }
        B10 = rd8(&TA[w][c][8*h]);
        B11 = rd8(&TA[w][c][16 + 8*h]);
        B20 = rd8(&TB[w][c][8*h]);
        B21 = rd8(&TB[w][c][16 + 8*h]);
    };

    // dual-chain Chebyshev step: 4 MFMAs per matrix (A hi/lo x B bf16)
    auto STEP = [&](float coef, float (&W1)[16], float (&W2)[16], bool dobuild) {
        f32x16 a1 = zz, a2 = zz;
        a1 = __builtin_amdgcn_mfma_f32_32x32x16_bf16(A1h0, B10, a1, 0,0,0);
        a2 = __builtin_amdgcn_mfma_f32_32x32x16_bf16(A2h0, B20, a2, 0,0,0);
        a1 = __builtin_amdgcn_mfma_f32_32x32x16_bf16(A1l0, B10, a1, 0,0,0);
        a2 = __builtin_amdgcn_mfma_f32_32x32x16_bf16(A2l0, B20, a2, 0,0,0);
        a1 = __builtin_amdgcn_mfma_f32_32x32x16_bf16(A1h1, B11, a1, 0,0,0);
        a2 = __builtin_amdgcn_mfma_f32_32x32x16_bf16(A2h1, B21, a2, 0,0,0);
        a1 = __builtin_amdgcn_mfma_f32_32x32x16_bf16(A1l1, B11, a1, 0,0,0);
        a2 = __builtin_amdgcn_mfma_f32_32x32x16_bf16(A2l1, B21, a2, 0,0,0);
        #pragma unroll
        for (int i = 0; i < 16; ++i) {
            float n1 = fmaf(2.f, a1[i], -W1[i]);
            float n2 = fmaf(2.f, a2[i], -W2[i]);
            W1[i] = n1; W2[i] = n2;
            P1[i] = fmaf(coef, n1, P1[i]);
            P2[i] = fmaf(coef, n2, P2[i]);
        }
        if (dobuild) {
            if (stdok) {
                BUILD(W1, B10, B11);
                BUILD(W2, B20, B21);
            } else {
                BUILD_LDS(W1, W2);
            }
        }
    };

    STEP(-0.22809412f, U1, U2, true);    // T2
    STEP( 0.07262391f, V1, V2, true);    // T3
    STEP(-0.02601347f, U1, U2, true);    // T4
    STEP( 0.00993906f, V1, V2, true);    // T5
    STEP(-0.00395568f, U1, U2, true);    // T6
    STEP( 0.00161931f, V1, V2, true);    // T7
    STEP(-0.00067670f, U1, U2, true);    // T8
    STEP( 0.00028728f, V1, V2, true);    // T9
    STEP(-0.00012348f, U1, U2, false);   // T10 (T11,T12 dropped: <=8e-5/eig)

    float s = 0.f;
    #pragma unroll
    for (int i = 0; i < 16; ++i) { float d = P1[i] - P2[i]; s = fmaf(d, d, s); }
    #pragma unroll
    for (int m = 32; m >= 1; m >>= 1)
        s += bperm((lane ^ m) << 2, s);
    if (lane == 0) bl[w] = valid * sqrtf(fmaxf(s, 0.f));

    __syncthreads();
    if (t == 0) {
        float sum = 0.f;
        #pragma unroll
        for (int i = 0; i < NW; ++i) sum += bl[i];
        atomicAdd(out, sum);
    }
}

extern "C" void kernel_launch(void* const* d_in, const int* in_sizes, int n_in,
                              void* d_out, int out_size, void* d_ws, size_t ws_size,
                              hipStream_t stream)
{
    const float* yhat = (const float*)d_in[0];
    const float* y    = (const float*)d_in[1];
    float* out = (float*)d_out;
    const int B = in_sizes[0] / 1024;   // 32*32 per matrix

    (void)hipMemsetAsync(out, 0, sizeof(float), stream);
    const int grid = (B + NW - 1) / NW;
    hipLaunchKernelGGL(geo_loss_mfma, dim3(grid), dim3(128), 0, stream,
                       yhat, y, out, B);
}